// Round 3
// baseline (282.296 us; speedup 1.0000x reference)
//
#include <hip/hip_runtime.h>
#include <math.h>

#define DIM 512
#define INTER 64
#define N_ROUTED 64
#define TOPK 6
#define NTOK 1024            // B*T
#define CAP 1024             // per-expert token list capacity (worst case)
#define TPW 8                // tokens per wave-chunk
#define GR 4                 // blocks per routed expert  (64*4 = 256 blocks)
#define GS 32                // blocks per shared expert  (2*32 = 64 blocks)

__device__ __forceinline__ void fma4(float4& o, float a, const float4& b) {
  o.x += a * b.x; o.y += a * b.y; o.z += a * b.z; o.w += a * b.w;
}

// ---------------------------------------------------------------------------
// Transpose g_w [64][512] -> g_wT [512][64] so gate loads are coalesced.
// ---------------------------------------------------------------------------
__global__ __launch_bounds__(256) void transpose_gw(
    const float* __restrict__ g_w, float* __restrict__ g_wT) {
  __shared__ float tile[32][33];
  const int bd = blockIdx.x;          // 0..15 (d tiles)
  const int be = blockIdx.y;          // 0..1  (e tiles)
  const int c = threadIdx.x & 31;
  const int r = threadIdx.x >> 5;     // 0..7
  #pragma unroll
  for (int k = 0; k < 4; ++k)
    tile[r + k * 8][c] = g_w[(be * 32 + r + k * 8) * DIM + bd * 32 + c];
  __syncthreads();
  #pragma unroll
  for (int k = 0; k < 4; ++k)
    g_wT[(bd * 32 + r + k * 8) * N_ROUTED + be * 32 + c] = tile[c][r + k * 8];
}

// ---------------------------------------------------------------------------
// Gate: one wave per token, lane = routed expert. Coalesced g_wT loads.
// Softmax over 64 lanes; iterative top-6 argmax on (prob + bias), first-index
// tie-break (matches lax.top_k). NO global atomics: winning lane writes the
// dense per-token choice arrays.
// ---------------------------------------------------------------------------
__global__ __launch_bounds__(256) void gate_kernel(
    const float* __restrict__ x, const float* __restrict__ g_wT,
    const float* __restrict__ gate_bias,
    int* __restrict__ choice_idx, float* __restrict__ choice_w) {
  const int lane = threadIdx.x & 63;
  const int t = (blockIdx.x * 256 + threadIdx.x) >> 6;   // token id 0..1023
  const float* xr = x + (size_t)t * DIM;

  float acc = 0.f;
  for (int d = 0; d < DIM; d += 4) {
    const float4 xv = *(const float4*)(xr + d);
    const float g0 = g_wT[(d + 0) * N_ROUTED + lane];
    const float g1 = g_wT[(d + 1) * N_ROUTED + lane];
    const float g2 = g_wT[(d + 2) * N_ROUTED + lane];
    const float g3 = g_wT[(d + 3) * N_ROUTED + lane];
    acc += xv.x * g0 + xv.y * g1 + xv.z * g2 + xv.w * g3;
  }

  float m = acc;
  for (int off = 32; off; off >>= 1) m = fmaxf(m, __shfl_xor(m, off, 64));
  const float p = expf(acc - m);
  float s = p;
  for (int off = 32; off; off >>= 1) s += __shfl_xor(s, off, 64);
  const float prob = p / s;
  float biased = prob + gate_bias[lane];

  for (int k = 0; k < TOPK; ++k) {
    float v = biased;
    int idx = lane;
    for (int off = 1; off < 64; off <<= 1) {
      const float ov = __shfl_xor(v, off, 64);
      const int oi = __shfl_xor(idx, off, 64);
      if (ov > v || (ov == v && oi < idx)) { v = ov; idx = oi; }
    }
    if (lane == idx) {
      choice_idx[t * TOPK + k] = lane;
      choice_w[t * TOPK + k] = prob;    // ROUTE_SCALE == 1.0
      biased = -INFINITY;
    }
  }
}

// ---------------------------------------------------------------------------
// Build per-expert token lists from the dense choices. One block per expert;
// LDS counter only (no contended global atomics).
// ---------------------------------------------------------------------------
__global__ __launch_bounds__(256) void build_lists(
    const int* __restrict__ choice_idx, const float* __restrict__ choice_w,
    int* __restrict__ cnt, int* __restrict__ tlist, float* __restrict__ wlist) {
  __shared__ int lcnt;
  const int e = blockIdx.x;
  if (threadIdx.x == 0) lcnt = 0;
  __syncthreads();
  for (int j = threadIdx.x; j < NTOK * TOPK; j += 256) {
    if (choice_idx[j] == e) {
      const int pos = atomicAdd(&lcnt, 1);
      tlist[e * CAP + pos] = j / TOPK;
      wlist[e * CAP + pos] = choice_w[j];
    }
  }
  __syncthreads();
  if (threadIdx.x == 0) cnt[e] = lcnt;
}

// ---------------------------------------------------------------------------
// Expert FFN, barrier-free. Block = (expert, token-group); each of the 4
// waves owns TPW=8 tokens end-to-end: full-depth h1/h3 in registers
// (lane = inter unit), silu*h3*route_weight into a wave-private LDS slab,
// then the w2 combine with lane owning 8 output columns (activation b128
// broadcast reused across 8 cols), atomicAdd scatter into zeroed out.
// ---------------------------------------------------------------------------
__global__ __launch_bounds__(256) void ffn_kernel(
    const float* __restrict__ x,
    const float* __restrict__ w1, const float* __restrict__ w2,
    const float* __restrict__ w3,
    const int* __restrict__ cnt, const int* __restrict__ tlist,
    const float* __restrict__ wlist,
    float* __restrict__ out) {
  __shared__ float as_[4][TPW][INTER];   // 8 KB, wave-private slabs

  const int tid = threadIdx.x;
  const int lane = tid & 63;
  const int w = __builtin_amdgcn_readfirstlane(tid >> 6);

  int e, g, G, n;
  const int* mylist = nullptr;
  const float* mywl = nullptr;
  const bool shared_e = (blockIdx.x >= N_ROUTED * GR);
  if (!shared_e) {
    const int r = blockIdx.x >> 2;       // GR = 4
    g = blockIdx.x & 3;
    e = r + 2; G = GR; n = cnt[r];
    mylist = tlist + r * CAP;
    mywl = wlist + r * CAP;
  } else {
    const int sb = blockIdx.x - N_ROUTED * GR;
    e = sb >> 5; g = sb & 31; G = GS; n = NTOK;
  }
  const int m = (n > g) ? (n - g + G - 1) / G : 0;

  const float* w1p = w1 + (size_t)e * DIM * INTER + lane;
  const float* w3p = w3 + (size_t)e * DIM * INTER + lane;
  const float* w2e = w2 + (size_t)e * INTER * DIM;
  const int c0 = lane * 8;

  for (int base = w * TPW; base < m; base += 4 * TPW) {
    const int nv = min(TPW, m - base);

    int tk[TPW];
    float twt[TPW];
    const float* xp[TPW];
    #pragma unroll
    for (int t = 0; t < TPW; ++t) {
      const int jl = base + t;
      if (jl < m) {
        const int j = g + jl * G;
        if (shared_e) { tk[t] = j; twt[t] = 1.0f; }
        else          { tk[t] = mylist[j]; twt[t] = mywl[j]; }
      } else { tk[t] = 0; twt[t] = 0.0f; }
      xp[t] = x + (size_t)tk[t] * DIM;
    }

    // ---- phase A: h1/h3 full depth, lane = inter unit ----
    float p1[TPW], p3[TPW];
    #pragma unroll
    for (int t = 0; t < TPW; ++t) { p1[t] = 0.f; p3[t] = 0.f; }
    #pragma unroll 2
    for (int d = 0; d < DIM; d += 4) {
      const float a0 = w1p[(d + 0) << 6];
      const float a1 = w1p[(d + 1) << 6];
      const float a2 = w1p[(d + 2) << 6];
      const float a3 = w1p[(d + 3) << 6];
      const float b0 = w3p[(d + 0) << 6];
      const float b1 = w3p[(d + 1) << 6];
      const float b2 = w3p[(d + 2) << 6];
      const float b3 = w3p[(d + 3) << 6];
      #pragma unroll
      for (int t = 0; t < TPW; ++t) {
        const float4 xv = *(const float4*)(xp[t] + d);   // wave-uniform
        p1[t] += xv.x * a0 + xv.y * a1 + xv.z * a2 + xv.w * a3;
        p3[t] += xv.x * b0 + xv.y * b1 + xv.z * b2 + xv.w * b3;
      }
    }
    #pragma unroll
    for (int t = 0; t < TPW; ++t) {
      const float h1 = p1[t];
      as_[w][t][lane] = (h1 / (1.0f + expf(-h1))) * p3[t] * twt[t];
    }
    // wave-private slab: no barrier needed (compiler inserts lgkmcnt)

    // ---- phase B: lane owns output cols c0..c0+7 ----
    float4 o0[TPW], o1[TPW];
    #pragma unroll
    for (int t = 0; t < TPW; ++t) {
      o0[t] = make_float4(0.f, 0.f, 0.f, 0.f);
      o1[t] = make_float4(0.f, 0.f, 0.f, 0.f);
    }
    #pragma unroll 4
    for (int ii = 0; ii < INTER; ii += 4) {
      const float4 wa0 = *(const float4*)(w2e + (ii + 0) * DIM + c0);
      const float4 wa1 = *(const float4*)(w2e + (ii + 0) * DIM + c0 + 4);
      const float4 wb0 = *(const float4*)(w2e + (ii + 1) * DIM + c0);
      const float4 wb1 = *(const float4*)(w2e + (ii + 1) * DIM + c0 + 4);
      const float4 wc0 = *(const float4*)(w2e + (ii + 2) * DIM + c0);
      const float4 wc1 = *(const float4*)(w2e + (ii + 2) * DIM + c0 + 4);
      const float4 wd0 = *(const float4*)(w2e + (ii + 3) * DIM + c0);
      const float4 wd1 = *(const float4*)(w2e + (ii + 3) * DIM + c0 + 4);
      #pragma unroll
      for (int t = 0; t < TPW; ++t) {
        const float4 av = *(const float4*)&as_[w][t][ii];  // broadcast b128
        fma4(o0[t], av.x, wa0); fma4(o1[t], av.x, wa1);
        fma4(o0[t], av.y, wb0); fma4(o1[t], av.y, wb1);
        fma4(o0[t], av.z, wc0); fma4(o1[t], av.z, wc1);
        fma4(o0[t], av.w, wd0); fma4(o1[t], av.w, wd1);
      }
    }

    for (int t = 0; t < nv; ++t) {
      float* op = out + (size_t)tk[t] * DIM + c0;
      atomicAdd(op + 0, o0[t].x); atomicAdd(op + 1, o0[t].y);
      atomicAdd(op + 2, o0[t].z); atomicAdd(op + 3, o0[t].w);
      atomicAdd(op + 4, o1[t].x); atomicAdd(op + 5, o1[t].y);
      atomicAdd(op + 6, o1[t].z); atomicAdd(op + 7, o1[t].w);
    }
  }
}

extern "C" void kernel_launch(void* const* d_in, const int* in_sizes, int n_in,
                              void* d_out, int out_size, void* d_ws, size_t ws_size,
                              hipStream_t stream) {
  const float* x         = (const float*)d_in[0];
  const float* g_w       = (const float*)d_in[1];
  const float* gate_bias = (const float*)d_in[2];
  const float* w1        = (const float*)d_in[3];
  const float* w2        = (const float*)d_in[4];
  const float* w3        = (const float*)d_in[5];
  float* out = (float*)d_out;

  char* ws = (char*)d_ws;
  int*   cnt     = (int*)ws;                                  // 64 ints (pad 1KB)
  int*   tlist   = (int*)(ws + 1024);                         // 64*1024 ints
  float* wlist   = (float*)(ws + 1024 + N_ROUTED * CAP * 4);  // 64*1024 floats
  float* g_wT    = (float*)(ws + 1024 + N_ROUTED * CAP * 8);  // 512*64 floats
  int*   chidx   = (int*)(ws + 1024 + N_ROUTED * CAP * 8 + DIM * N_ROUTED * 4);
  float* chw     = (float*)((char*)chidx + NTOK * TOPK * 4);

  hipMemsetAsync(out, 0, (size_t)out_size * sizeof(float), stream);

  dim3 tg(DIM / 32, N_ROUTED / 32);
  transpose_gw<<<tg, 256, 0, stream>>>(g_w, g_wT);
  gate_kernel<<<NTOK / 4, 256, 0, stream>>>(x, g_wT, gate_bias, chidx, chw);
  build_lists<<<N_ROUTED, 256, 0, stream>>>(chidx, chw, cnt, tlist, wlist);
  ffn_kernel<<<N_ROUTED * GR + 2 * GS, 256, 0, stream>>>(
      x, w1, w2, w3, cnt, tlist, wlist, out);
}

// Round 4
// 211.366 us; speedup vs baseline: 1.3356x; 1.3356x over previous
//
#include <hip/hip_runtime.h>
#include <math.h>

#define DIM 512
#define INTER 64
#define N_ROUTED 64
#define TOPK 6
#define NTOK 1024            // B*T
#define CAP 1024             // per-expert token list capacity (worst case)
#define TTILE 16             // tokens per block tile
#define GR 6                 // blocks per routed expert  (64*6 = 384)
#define GS 64                // blocks per shared expert  (2*64 = 128)

// ---------------------------------------------------------------------------
// Transpose g_w [64][512] -> g_wT [512][64] so gate loads are coalesced.
// ---------------------------------------------------------------------------
__global__ __launch_bounds__(256) void transpose_gw(
    const float* __restrict__ g_w, float* __restrict__ g_wT) {
  __shared__ float tile[32][33];
  const int bd = blockIdx.x;          // 0..15 (d tiles)
  const int be = blockIdx.y;          // 0..1  (e tiles)
  const int c = threadIdx.x & 31;
  const int r = threadIdx.x >> 5;     // 0..7
  #pragma unroll
  for (int k = 0; k < 4; ++k)
    tile[r + k * 8][c] = g_w[(be * 32 + r + k * 8) * DIM + bd * 32 + c];
  __syncthreads();
  #pragma unroll
  for (int k = 0; k < 4; ++k)
    g_wT[(bd * 32 + r + k * 8) * N_ROUTED + be * 32 + c] = tile[c][r + k * 8];
}

// ---------------------------------------------------------------------------
// Gate: one wave per token, lane = routed expert, coalesced g_wT loads.
// Softmax across 64 lanes; iterative top-6 argmax on (prob + bias),
// first-index tie-break (matches lax.top_k). No atomics: dense choice arrays.
// ---------------------------------------------------------------------------
__global__ __launch_bounds__(256) void gate_kernel(
    const float* __restrict__ x, const float* __restrict__ g_wT,
    const float* __restrict__ gate_bias,
    int* __restrict__ choice_idx, float* __restrict__ choice_w) {
  const int lane = threadIdx.x & 63;
  const int t = (blockIdx.x * 256 + threadIdx.x) >> 6;   // token id 0..1023
  const float* xr = x + (size_t)t * DIM;

  float acc = 0.f;
  for (int d = 0; d < DIM; d += 4) {
    const float4 xv = *(const float4*)(xr + d);
    const float g0 = g_wT[(d + 0) * N_ROUTED + lane];
    const float g1 = g_wT[(d + 1) * N_ROUTED + lane];
    const float g2 = g_wT[(d + 2) * N_ROUTED + lane];
    const float g3 = g_wT[(d + 3) * N_ROUTED + lane];
    acc += xv.x * g0 + xv.y * g1 + xv.z * g2 + xv.w * g3;
  }

  float m = acc;
  for (int off = 32; off; off >>= 1) m = fmaxf(m, __shfl_xor(m, off, 64));
  const float p = expf(acc - m);
  float s = p;
  for (int off = 32; off; off >>= 1) s += __shfl_xor(s, off, 64);
  const float prob = p / s;
  float biased = prob + gate_bias[lane];

  for (int k = 0; k < TOPK; ++k) {
    float v = biased;
    int idx = lane;
    for (int off = 1; off < 64; off <<= 1) {
      const float ov = __shfl_xor(v, off, 64);
      const int oi = __shfl_xor(idx, off, 64);
      if (ov > v || (ov == v && oi < idx)) { v = ov; idx = oi; }
    }
    if (lane == idx) {
      choice_idx[t * TOPK + k] = lane;
      choice_w[t * TOPK + k] = prob;    // ROUTE_SCALE == 1.0
      biased = -INFINITY;
    }
  }
}

// ---------------------------------------------------------------------------
// Build per-expert token lists. SINGLE block, 1024 threads, LDS counters.
// 6144 entries / 1024 threads = 6 iterations. ~2 us.
// ---------------------------------------------------------------------------
__global__ __launch_bounds__(1024) void build_lists(
    const int* __restrict__ choice_idx, const float* __restrict__ choice_w,
    int* __restrict__ cnt, int* __restrict__ tlist, float* __restrict__ wlist) {
  __shared__ int lcnt[N_ROUTED];
  if (threadIdx.x < N_ROUTED) lcnt[threadIdx.x] = 0;
  __syncthreads();
  for (int j = threadIdx.x; j < NTOK * TOPK; j += 1024) {
    const int e = choice_idx[j];
    const int pos = atomicAdd(&lcnt[e], 1);
    tlist[e * CAP + pos] = j / TOPK;
    wlist[e * CAP + pos] = choice_w[j];
  }
  __syncthreads();
  if (threadIdx.x < N_ROUTED) cnt[threadIdx.x] = lcnt[threadIdx.x];
}

// ---------------------------------------------------------------------------
// Expert FFN: block = (expert, token-group), 16-token LDS tile.
// Phase A: wave w computes tokens 4w..4w+3 full-depth (lane = inter unit),
//          folds silu*h3*route_weight into as_.
// Phase B: thread owns output cols (tid, tid+256) for all 16 tokens;
//          coalesced atomicAdd scatter (lane = consecutive col).
// 36 KB LDS -> 4 blocks/CU; 3 barriers per tile.
// ---------------------------------------------------------------------------
__global__ __launch_bounds__(256, 4) void ffn_kernel(
    const float* __restrict__ x,
    const float* __restrict__ w1, const float* __restrict__ w2,
    const float* __restrict__ w3,
    const int* __restrict__ cnt, const int* __restrict__ tlist,
    const float* __restrict__ wlist,
    float* __restrict__ out) {
  __shared__ float xs[TTILE][DIM];      // 32 KB
  __shared__ float as_[TTILE][INTER];   // 4 KB
  __shared__ int   tok[TTILE];
  __shared__ float tw[TTILE];

  const int tid = threadIdx.x;
  const int lane = tid & 63;
  const int w = tid >> 6;

  int e, g, G, n;
  const int* mylist = nullptr;
  const float* mywl = nullptr;
  const bool shared_e = (blockIdx.x >= N_ROUTED * GR);
  if (!shared_e) {
    const int r = blockIdx.x / GR;
    g = blockIdx.x - r * GR;
    e = r + 2; G = GR; n = cnt[r];
    mylist = tlist + r * CAP;
    mywl = wlist + r * CAP;
  } else {
    const int sb = blockIdx.x - N_ROUTED * GR;
    e = sb >> 6; g = sb & 63; G = GS; n = NTOK;
  }
  const int m = (n > g) ? (n - g + G - 1) / G : 0;

  const float* w1p = w1 + (size_t)e * DIM * INTER + lane;
  const float* w3p = w3 + (size_t)e * DIM * INTER + lane;
  const float* w2e = w2 + (size_t)e * INTER * DIM;

  for (int base = 0; base < m; base += TTILE) {
    const int mt = min(TTILE, m - base);
    if (tid < TTILE) {
      if (tid < mt) {
        const int j = g + (base + tid) * G;
        if (shared_e) { tok[tid] = j; tw[tid] = 1.0f; }
        else          { tok[tid] = mylist[j]; tw[tid] = mywl[j]; }
      } else { tok[tid] = 0; tw[tid] = 0.0f; }
    }
    __syncthreads();

    // stage 16 token rows (coalesced float4)
    #pragma unroll
    for (int k = 0; k < 8; ++k) {
      const int fidx = tid + k * 256;     // 0..2047 float4 slots
      const int row = fidx >> 7;
      const int c4 = fidx & 127;
      *(float4*)&xs[row][c4 * 4] =
          *(const float4*)(x + (size_t)tok[row] * DIM + c4 * 4);
    }
    __syncthreads();

    // ---- phase A: wave w owns tokens 4w..4w+3, full depth ----
    const int t0 = w * 4;
    float p1[4] = {0.f, 0.f, 0.f, 0.f};
    float p3[4] = {0.f, 0.f, 0.f, 0.f};
    for (int d = 0; d < DIM; d += 4) {
      const float a0 = w1p[(d + 0) << 6];
      const float a1 = w1p[(d + 1) << 6];
      const float a2 = w1p[(d + 2) << 6];
      const float a3 = w1p[(d + 3) << 6];
      const float b0 = w3p[(d + 0) << 6];
      const float b1 = w3p[(d + 1) << 6];
      const float b2 = w3p[(d + 2) << 6];
      const float b3 = w3p[(d + 3) << 6];
      #pragma unroll
      for (int t = 0; t < 4; ++t) {
        const float4 xv = *(const float4*)&xs[t0 + t][d];   // LDS broadcast
        p1[t] += xv.x * a0 + xv.y * a1 + xv.z * a2 + xv.w * a3;
        p3[t] += xv.x * b0 + xv.y * b1 + xv.z * b2 + xv.w * b3;
      }
    }
    #pragma unroll
    for (int t = 0; t < 4; ++t) {
      const float h1 = p1[t];
      as_[t0 + t][lane] = (h1 / (1.0f + expf(-h1))) * p3[t] * tw[t0 + t];
    }
    __syncthreads();

    // ---- phase B: thread owns cols tid and tid+256 for all tokens ----
    float o0[TTILE], o1[TTILE];
    #pragma unroll
    for (int t = 0; t < TTILE; ++t) { o0[t] = 0.f; o1[t] = 0.f; }
    for (int ii = 0; ii < INTER; ii += 4) {
      const float u0 = w2e[(ii + 0) * DIM + tid];
      const float u1 = w2e[(ii + 1) * DIM + tid];
      const float u2 = w2e[(ii + 2) * DIM + tid];
      const float u3 = w2e[(ii + 3) * DIM + tid];
      const float v0 = w2e[(ii + 0) * DIM + tid + 256];
      const float v1 = w2e[(ii + 1) * DIM + tid + 256];
      const float v2 = w2e[(ii + 2) * DIM + tid + 256];
      const float v3 = w2e[(ii + 3) * DIM + tid + 256];
      #pragma unroll
      for (int t = 0; t < TTILE; ++t) {
        const float4 av = *(const float4*)&as_[t][ii];
        o0[t] += av.x * u0 + av.y * u1 + av.z * u2 + av.w * u3;
        o1[t] += av.x * v0 + av.y * v1 + av.z * v2 + av.w * v3;
      }
    }
    for (int t = 0; t < mt; ++t) {
      atomicAdd(&out[(size_t)tok[t] * DIM + tid], o0[t]);
      atomicAdd(&out[(size_t)tok[t] * DIM + tid + 256], o1[t]);
    }
    __syncthreads();
  }
}

extern "C" void kernel_launch(void* const* d_in, const int* in_sizes, int n_in,
                              void* d_out, int out_size, void* d_ws, size_t ws_size,
                              hipStream_t stream) {
  const float* x         = (const float*)d_in[0];
  const float* g_w       = (const float*)d_in[1];
  const float* gate_bias = (const float*)d_in[2];
  const float* w1        = (const float*)d_in[3];
  const float* w2        = (const float*)d_in[4];
  const float* w3        = (const float*)d_in[5];
  float* out = (float*)d_out;

  char* ws = (char*)d_ws;
  int*   cnt     = (int*)ws;                                  // 64 ints (pad 1KB)
  int*   tlist   = (int*)(ws + 1024);                         // 64*1024 ints
  float* wlist   = (float*)(ws + 1024 + N_ROUTED * CAP * 4);  // 64*1024 floats
  float* g_wT    = (float*)(ws + 1024 + N_ROUTED * CAP * 8);  // 512*64 floats
  int*   chidx   = (int*)(ws + 1024 + N_ROUTED * CAP * 8 + DIM * N_ROUTED * 4);
  float* chw     = (float*)((char*)chidx + NTOK * TOPK * 4);

  hipMemsetAsync(out, 0, (size_t)out_size * sizeof(float), stream);

  dim3 tg(DIM / 32, N_ROUTED / 32);
  transpose_gw<<<tg, 256, 0, stream>>>(g_w, g_wT);
  gate_kernel<<<NTOK / 4, 256, 0, stream>>>(x, g_wT, gate_bias, chidx, chw);
  build_lists<<<1, 1024, 0, stream>>>(chidx, chw, cnt, tlist, wlist);
  ffn_kernel<<<N_ROUTED * GR + 2 * GS, 256, 0, stream>>>(
      x, w1, w2, w3, cnt, tlist, wlist, out);
}